// Round 8
// baseline (293.282 us; speedup 1.0000x reference)
//
#include <hip/hip_runtime.h>

// FilteredNoise: DDSP filtered noise, FFT-free.
// zp[d] = (1/129)(fr0 + 2*sum_{k=1..64} fr_k cos(2*pi*k*d/129)), even-symmetric
// wir[j] = hann_periodic(j,129) * zp[(j-64) mod 129]; j=128 tap dropped (win=5.9e-4)
// out[b,64*fp+r] = sum_{dd=0..2} sum_s n[fp-dd][s] * w_x[63+64dd+r-s]   (padded coords)
// Conv via v_dot2_f32_f16 (2 MAC/instr, fp32 accum): wir stored REVERSED in f16,
// two copies offset by 1 half so every thread's pair stream is half2-aligned.
//   wrevA[x'] = w_x[254-x'],  wrevB[x'] = w_x[255-x']
// Thread handles 8 same-parity samples r = r0+2i; per (dd,t): 1 b32 w-load,
// 8 dot2 against an 8-register ring (constant indices, no movs).

typedef __fp16 half2_t __attribute__((ext_vector_type(2)));

#define NB 64
#define FTOT 4097
#define FCL 65
#define FL 64
#define SAMPLES 262144
#define OUT_FRAMES 4096
#define G 16                     // output frames per block
#define NF (G + 2)               // staged frames
#define NSH 36                   // nH row stride in half2 (144B: 16B-aligned, bank-staggered)
#define PWH 264                  // wrev row stride in halfs (132 dwords, %32=4 stagger)
#define BLOCKS_PER_B (OUT_FRAMES / G)   // 256

__device__ __forceinline__ float mod_sigmoid(float x) {
    float s = 1.0f / (1.0f + __expf(-x));
    return 2.0f * __expf(2.302585092994046f * __logf(s)) + 1e-7f;   // 2*s^ln(10)+1e-7
}

__device__ __forceinline__ float rdlane(float v, int k) {
    return __int_as_float(__builtin_amdgcn_readlane(__float_as_int(v), k));
}

__global__ __launch_bounds__(128) void fn_kernel(
    const float* __restrict__ coeff,   // (64, 4097, 65)
    const float* __restrict__ noise,   // (64, 4097, 64)
    float* __restrict__ out)           // (64, 262144)
{
    __shared__ __align__(16) float costab[132];
    __shared__ __align__(16) half2_t nH[NF * NSH];       // noise*2-1 as f16 pairs
    __shared__ __align__(16) __fp16 wrevA[NF * PWH];     // reversed wir, even-phase
    __shared__ __align__(16) __fp16 wrevB[NF * PWH];     // reversed wir, odd-phase

    const int tid  = threadIdx.x;
    const int lane = tid & 63;
    const int wv   = tid >> 6;                           // wave 0..1
    const int blk  = blockIdx.x;
    const int b    = blk / BLOCKS_PER_B;
    const int cg   = blk % BLOCKS_PER_B;
    const int fp0  = cg * G;
    const int fbase = fp0 - 2;

    // zero wrevA/B (pads must be 0); NF*PWH halfs = 594 float4 each
    for (int i = tid; i < (NF * PWH) / 8; i += 128) {
        ((float4*)wrevA)[i] = make_float4(0.f, 0.f, 0.f, 0.f);
        ((float4*)wrevB)[i] = make_float4(0.f, 0.f, 0.f, 0.f);
    }
    for (int i = tid; i < 129; i += 128)
        costab[i] = __cosf(6.283185307179586f * (float)i * (1.0f / 129.0f));

    // stage noise -> f16 pairs (zero where frame < 0)
    for (int i = tid; i < NF * 16; i += 128) {
        int q = i >> 4, g = i & 15;                      // g-th float4 = samples 4g..4g+3
        int f = fbase + q;
        float4 u = make_float4(0.5f, 0.5f, 0.5f, 0.5f);  // maps to n=0
        if (f >= 0)
            u = ((const float4*)(noise + ((size_t)b * FTOT + f) * FL))[g];
        half2_t h0 = __builtin_amdgcn_cvt_pkrtz(2.f*u.x-1.f, 2.f*u.y-1.f);
        half2_t h1 = __builtin_amdgcn_cvt_pkrtz(2.f*u.z-1.f, 2.f*u.w-1.f);
        nH[q * NSH + 2 * g]     = h0;
        nH[q * NSH + 2 * g + 1] = h1;
    }

    // preload this wave's 9 frame spectra (frames wv, wv+2, ..., wv+16)
    float frv[9], f64v[9];
    #pragma unroll
    for (int i = 0; i < 9; ++i) {
        int f = fbase + wv + 2 * i;
        if (f < 0) f = 0;                        // garbage wir nulled via n=0
        const float* row = coeff + ((size_t)b * FTOT + f) * FCL;
        frv[i]  = row[lane];
        f64v[i] = row[64];
    }
    #pragma unroll
    for (int i = 0; i < 9; ++i) {
        frv[i]  = mod_sigmoid(frv[i]);
        f64v[i] = mod_sigmoid(f64v[i]);
    }

    __syncthreads();   // zeros + nH + costab visible

    // transform: shared Chebyshev recurrence across the wave's 9 frames
    {
        float c  = costab[lane];
        float c2 = 2.0f * c;
        float cp = 1.0f;
        float ck = c;
        float S[9];
        #pragma unroll
        for (int i = 0; i < 9; ++i) S[i] = 0.5f * rdlane(frv[i], 0);
        #pragma unroll 8
        for (int k = 1; k < 64; ++k) {
            #pragma unroll
            for (int i = 0; i < 9; ++i)
                S[i] = __builtin_fmaf(rdlane(frv[i], k), ck, S[i]);
            float cn = __builtin_fmaf(c2, ck, -cp);
            cp = ck; ck = cn;
        }
        #pragma unroll
        for (int i = 0; i < 9; ++i)
            S[i] = __builtin_fmaf(f64v[i], ck, S[i]);    // k=64, ck=cos(64*theta)
        // window + reversed f16 scatter into both phase copies
        float w1f = 0.5f - 0.5f * costab[64 + lane];     // win at j=64+d (x=127+d)
        float w2f = 0.5f - 0.5f * costab[64 - lane];     // win at j=64-d (x=127-d)
        #pragma unroll
        for (int i = 0; i < 9; ++i) {
            int fi = wv + 2 * i;
            float zp = S[i] * (2.0f / 129.0f);
            __fp16 h1 = (__fp16)(w1f * zp);              // w_x[127+lane]
            __fp16 h2 = (__fp16)(w2f * zp);              // w_x[127-lane]
            wrevA[fi * PWH + 127 - lane] = h1;           // x'A = 254-(127+lane)
            wrevA[fi * PWH + 127 + lane] = h2;           // x'A = 254-(127-lane)
            wrevB[fi * PWH + 128 - lane] = h1;           // x'B = 255-(127+lane)
            wrevB[fi * PWH + 128 + lane] = h2;
        }
    }
    __syncthreads();

    // conv + OLA: 8 same-parity samples/thread, dot2 with 8-reg rolling ring
    {
        const int chunk = tid >> 3;              // frame within block (0..15)
        const int tf    = tid & 7;               // thread-in-frame
        const int par   = tf & 1;
        const int r0    = (tf >> 1) * 16 + par;  // first sample (stride-2 set)
        float acc[8];
        #pragma unroll
        for (int i = 0; i < 8; ++i) acc[i] = 0.0f;

        #pragma unroll
        for (int dd = 0; dd < 3; ++dd) {
            const int q  = chunk + 2 - dd;       // staged index of frame fp-dd
            const int C0 = 63 + 64 * dd + r0;    // padded w index for r0, s=0
            const __fp16* wr = (C0 & 1) ? &wrevB[q * PWH] : &wrevA[q * PWH];
            const int h0 = ((C0 & 1) ? (255 - C0) : (254 - C0)) >> 1;  // half2 base
            const half2_t* wrh  = (const half2_t*)wr;
            const half2_t* nrow = &nH[q * NSH];

            half2_t W[8];
            #pragma unroll
            for (int j = 0; j < 7; ++j) W[j] = wrh[h0 - 7 + j];   // indices h0-7..h0-1
            #pragma unroll
            for (int t = 0; t < 32; ++t) {
                W[(t + 7) & 7] = wrh[h0 + t];
                half2_t a = nrow[t];             // (n[2t], n[2t+1])
                #pragma unroll
                for (int i = 0; i < 8; ++i)      // b = wrh[h0 + t - i]
                    acc[i] = __builtin_amdgcn_fdot2(a, W[(t + 7 - i) & 7], acc[i], false);
            }
        }

        float* op = out + (size_t)b * SAMPLES + (size_t)(fp0 + chunk) * 64 + r0;
        #pragma unroll
        for (int i = 0; i < 8; ++i) op[2 * i] = acc[i];
    }
}

extern "C" void kernel_launch(void* const* d_in, const int* in_sizes, int n_in,
                              void* d_out, int out_size, void* d_ws, size_t ws_size,
                              hipStream_t stream) {
    const float* coeff = (const float*)d_in[0];
    const float* noise = (const float*)d_in[1];
    float* out = (float*)d_out;
    dim3 grid(NB * BLOCKS_PER_B);   // 64 * 256 = 16384 blocks, 128 threads
    fn_kernel<<<grid, 128, 0, stream>>>(coeff, noise, out);
}